// Round 7
// baseline (247.441 us; speedup 1.0000x reference)
//
#include <hip/hip_runtime.h>
#include <hip/hip_fp16.h>

// Problem constants (from reference)
#define BATCH 2
#define NS 128        // input spatial dim (X=Y=Z=128)
#define NB 64         // bricks per dim (2x2x2 voxel bricks, fallback path)
#define ND 96         // output grid per spatial dim

constexpr int PPB   = ND * ND * ND;            // 884736 points per batch
constexpr int TOTAL = BATCH * PPB;             // 1769472
constexpr int BRICKS_PER_BATCH = NB * NB * NB; // 262144
constexpr int TOTAL_BRICKS = BATCH * BRICKS_PER_BATCH;
constexpr size_t WS_BRICKS = (size_t)TOTAL_BRICKS * 64;            // 33.55 MB
constexpr int ENTRIES_PER_BATCH = NS * NS * NS;                    // 2097152
constexpr size_t WS_R4 = (size_t)BATCH * ENTRIES_PER_BATCH * 32;   // 134.2 MB

// native clang vector type: accepted by __builtin_nontemporal_*
typedef float fx4 __attribute__((ext_vector_type(4)));

__device__ __forceinline__ float4 f4_lerp(float4 a, float4 b, float t) {
    float4 r;
    r.x = fmaf(b.x - a.x, t, a.x);
    r.y = fmaf(b.y - a.y, t, a.y);
    r.z = fmaf(b.z - a.z, t, a.z);
    r.w = fmaf(b.w - a.w, t, a.w);
    return r;
}

__device__ __forceinline__ uint2 pack_h4(float4 v) {
    __half2 h0 = __float22half2_rn(make_float2(v.x, v.y));
    __half2 h1 = __float22half2_rn(make_float2(v.z, v.w));
    uint2 p;
    p.x = *(const unsigned int*)&h0;
    p.y = *(const unsigned int*)&h1;
    return p;
}

__device__ __forceinline__ float4 unpack_h4(unsigned int a, unsigned int b) {
    float2 f0 = __half22float2(*(const __half2*)&a);
    float2 f1 = __half22float2(*(const __half2*)&b);
    return make_float4(f0.x, f0.y, f1.x, f1.y);
}

// =====================================================================
// R4 path: per-voxel (y,z) 2x2 neighborhood table, 32B/entry, x fastest.
// entry(b,y,z,x) = voxels (x, y, z),(x, y, z+1'),(x, y+1', z),(x, y+1', z+1')
// with y+1' = min(y+1,127), z+1' = min(z+1,127) (replicate baked in).
// Layout: uint4 pair per entry; lo = [(y,z)|(y,z+1')], hi = [(y+1',z)|(y+1',z+1')]
// =====================================================================
__global__ __launch_bounds__(256) void build_r4_table(
    const fx4* __restrict__ in, uint4* __restrict__ tab)
{
    int g = blockIdx.x * 256 + threadIdx.x;          // entry id, grid exact
    int b = g >> 21;
    int r = g & ((1 << 21) - 1);
    int x = r & 127;
    int z = (r >> 7) & 127;
    int y = r >> 14;
    int y1 = min(y + 1, NS - 1);
    int z1 = min(z + 1, NS - 1);

    const fx4* __restrict__ row = in + (((size_t)b * NS + x) * NS) * NS;
    fx4 v00 = row[(size_t)y  * NS + z ];
    fx4 v01 = row[(size_t)y  * NS + z1];
    fx4 v10 = row[(size_t)y1 * NS + z ];
    fx4 v11 = row[(size_t)y1 * NS + z1];

    uint2 p00 = pack_h4(make_float4(v00.x, v00.y, v00.z, v00.w));
    uint2 p01 = pack_h4(make_float4(v01.x, v01.y, v01.z, v01.w));
    uint2 p10 = pack_h4(make_float4(v10.x, v10.y, v10.z, v10.w));
    uint2 p11 = pack_h4(make_float4(v11.x, v11.y, v11.z, v11.w));

    tab[2 * g + 0] = make_uint4(p00.x, p00.y, p01.x, p01.y);
    tab[2 * g + 1] = make_uint4(p10.x, p10.y, p11.x, p11.y);
}

// interpolate one point from the R4 table (one batch's sub-table)
__device__ __forceinline__ float4 sample_r4(
    const uint4* __restrict__ tb, float cx, float cy, float cz)
{
    const float fx = floorf(cx), fy = floorf(cy), fz = floorf(cz);
    const float wx = cx - fx;
    // boundary: fy<0 => both y-corners are voxel 0, but entry holds (0,1) -> force w=0
    const float wy = (fy < 0.f) ? 0.f : (cy - fy);
    const float wz = (fz < 0.f) ? 0.f : (cz - fz);

    int x0 = max(0, min((int)fx,     NS - 1));
    int x1 = max(0, min((int)fx + 1, NS - 1));
    int y0 = max(0, min((int)fy,     NS - 1));
    int z0 = max(0, min((int)fz,     NS - 1));

    int ebase = ((y0 << 7) + z0) << 7;    // entry index of (y0,z0,x=0)
    const uint4* e0 = tb + 2 * (ebase + x0);
    const uint4* e1 = tb + 2 * (ebase + x1);

    uint4 lo0 = e0[0], hi0 = e0[1];       // x0: (y0,z0)(y0,z1) | (y1,z0)(y1,z1)
    uint4 lo1 = e1[0], hi1 = e1[1];       // x1

    float4 a00 = unpack_h4(lo0.x, lo0.y), a01 = unpack_h4(lo0.z, lo0.w);
    float4 a10 = unpack_h4(hi0.x, hi0.y), a11 = unpack_h4(hi0.z, hi0.w);
    float4 b00 = unpack_h4(lo1.x, lo1.y), b01 = unpack_h4(lo1.z, lo1.w);
    float4 b10 = unpack_h4(hi1.x, hi1.y), b11 = unpack_h4(hi1.z, hi1.w);

    float4 cA0 = f4_lerp(a00, a01, wz);   // y0 row, x0
    float4 cA1 = f4_lerp(a10, a11, wz);   // y1 row, x0
    float4 cB0 = f4_lerp(b00, b01, wz);
    float4 cB1 = f4_lerp(b10, b11, wz);
    float4 cA  = f4_lerp(cA0, cA1, wy);
    float4 cB  = f4_lerp(cB0, cB1, wy);
    return f4_lerp(cA, cB, wx);
}

__device__ __forceinline__ void nt_store4(float4 v, fx4* p) {
    fx4 t; t.x = v.x; t.y = v.y; t.z = v.z; t.w = v.w;
    __builtin_nontemporal_store(t, p);
}

__global__ __launch_bounds__(256) void resample_r4(
    const uint4* __restrict__ tab,
    const float* __restrict__ coords,
    fx4*         __restrict__ out)
{
    int idx = blockIdx.x * 256 + threadIdx.x;   // 0 .. PPB-1 (grid exact)
    const int idxB = idx + PPB;

    const float axc = coords[3 * idx + 0];
    const float ayc = coords[3 * idx + 1];
    const float azc = coords[3 * idx + 2];
    const float bxc = coords[3 * idxB + 0];
    const float byc = coords[3 * idxB + 1];
    const float bzc = coords[3 * idxB + 2];

    const uint4* tb0 = tab;
    const uint4* tb1 = tab + (size_t)ENTRIES_PER_BATCH * 2;

    float4 rA = sample_r4(tb0, axc, ayc, azc);
    float4 rB = sample_r4(tb1, bxc, byc, bzc);
    nt_store4(rA, &out[idx]);
    nt_store4(rB, &out[idxB]);
}

// =====================================================================
// Fallback 1: fp16 2x2x2 bricks (proven 86 µs path)
// =====================================================================
__global__ __launch_bounds__(256) void repack_fp16_bricks(
    const fx4* __restrict__ in, uint2* __restrict__ bricks)
{
    int g = blockIdx.x * 256 + threadIdx.x;
    int t = g >> 3;
    int l = g & 7;
    int lx = (l >> 2) & 1, ly = (l >> 1) & 1, lz = l & 1;
    int b  = t >> 18;
    int r  = t & 262143;
    int x  = ((r >> 12) << 1) + lx;
    int y  = (((r >> 6) & 63) << 1) + ly;
    int z  = ((r & 63) << 1) + lz;

    fx4 v = __builtin_nontemporal_load(&in[(((size_t)b * NS + x) * NS + y) * NS + z]);
    bricks[g] = pack_h4(make_float4(v.x, v.y, v.z, v.w));
}

__device__ __forceinline__ float4 vox_to_f4(uint2 v) {
    return unpack_h4(v.x, v.y);
}

__device__ __forceinline__ int brick_off(int x, int y, int z) {
    int bidx = (((x >> 1) * NB) + (y >> 1)) * NB + (z >> 1);
    return (bidx << 3) + ((x & 1) << 2) + ((y & 1) << 1) + (z & 1);
}

__global__ __launch_bounds__(256) void resample_bricks(
    const uint2* __restrict__ bricks,
    const float* __restrict__ coords,
    float4*      __restrict__ out)
{
    int idx = blockIdx.x * 256 + threadIdx.x;
    if (idx >= TOTAL) return;

    const float cx = coords[3 * idx + 0];
    const float cy = coords[3 * idx + 1];
    const float cz = coords[3 * idx + 2];
    const float fx = floorf(cx), fy = floorf(cy), fz = floorf(cz);
    const float wx = cx - fx, wy = cy - fy, wz = cz - fz;

    int x0 = max(0, min((int)fx,     NS - 1));
    int x1 = max(0, min((int)fx + 1, NS - 1));
    int y0 = max(0, min((int)fy,     NS - 1));
    int y1 = max(0, min((int)fy + 1, NS - 1));
    int z0 = max(0, min((int)fz,     NS - 1));
    int z1 = max(0, min((int)fz + 1, NS - 1));

    const uint2* __restrict__ wb =
        bricks + ((idx >= PPB) ? (size_t)BRICKS_PER_BATCH * 8 : 0);

    uint2 u000 = wb[brick_off(x0, y0, z0)], u001 = wb[brick_off(x0, y0, z1)];
    uint2 u010 = wb[brick_off(x0, y1, z0)], u011 = wb[brick_off(x0, y1, z1)];
    uint2 u100 = wb[brick_off(x1, y0, z0)], u101 = wb[brick_off(x1, y0, z1)];
    uint2 u110 = wb[brick_off(x1, y1, z0)], u111 = wb[brick_off(x1, y1, z1)];

    float4 c00 = f4_lerp(vox_to_f4(u000), vox_to_f4(u001), wz);
    float4 c01 = f4_lerp(vox_to_f4(u010), vox_to_f4(u011), wz);
    float4 c10 = f4_lerp(vox_to_f4(u100), vox_to_f4(u101), wz);
    float4 c11 = f4_lerp(vox_to_f4(u110), vox_to_f4(u111), wz);
    float4 c0 = f4_lerp(c00, c01, wy);
    float4 c1 = f4_lerp(c10, c11, wy);
    out[idx] = f4_lerp(c0, c1, wx);
}

// =====================================================================
// Fallback 2: direct fp32 gather (no workspace)
// =====================================================================
__global__ __launch_bounds__(256) void resample_direct(
    const float4* __restrict__ in,
    const float*  __restrict__ coords,
    float4*       __restrict__ out)
{
    int idx = blockIdx.x * blockDim.x + threadIdx.x;
    if (idx >= TOTAL) return;

    const float cx = coords[3 * idx + 0];
    const float cy = coords[3 * idx + 1];
    const float cz = coords[3 * idx + 2];
    const float fx = floorf(cx), fy = floorf(cy), fz = floorf(cz);
    const float wx = cx - fx, wy = cy - fy, wz = cz - fz;

    int x0 = max(0, min((int)fx,     NS - 1));
    int x1 = max(0, min((int)fx + 1, NS - 1));
    int y0 = max(0, min((int)fy,     NS - 1));
    int y1 = max(0, min((int)fy + 1, NS - 1));
    int z0 = max(0, min((int)fz,     NS - 1));
    int z1 = max(0, min((int)fz + 1, NS - 1));

    const int b = idx / PPB;
    const float4* __restrict__ inb = in + (size_t)b * (NS * NS * NS);
    const float4* r00 = inb + ((size_t)x0 * NS + y0) * NS;
    const float4* r01 = inb + ((size_t)x0 * NS + y1) * NS;
    const float4* r10 = inb + ((size_t)x1 * NS + y0) * NS;
    const float4* r11 = inb + ((size_t)x1 * NS + y1) * NS;

    float4 c00 = f4_lerp(r00[z0], r00[z1], wz);
    float4 c01 = f4_lerp(r01[z0], r01[z1], wz);
    float4 c10 = f4_lerp(r10[z0], r10[z1], wz);
    float4 c11 = f4_lerp(r11[z0], r11[z1], wz);
    float4 c0 = f4_lerp(c00, c01, wy);
    float4 c1 = f4_lerp(c10, c11, wy);
    out[idx] = f4_lerp(c0, c1, wx);
}

extern "C" void kernel_launch(void* const* d_in, const int* in_sizes, int n_in,
                              void* d_out, int out_size, void* d_ws, size_t ws_size,
                              hipStream_t stream) {
    const float* coords = (const float*)d_in[1];

    if (ws_size >= WS_R4) {
        uint4* tab = (uint4*)d_ws;
        int entries = BATCH * ENTRIES_PER_BATCH;          // 4194304
        build_r4_table<<<entries / 256, 256, 0, stream>>>((const fx4*)d_in[0], tab);
        resample_r4<<<PPB / 256, 256, 0, stream>>>(tab, coords, (fx4*)d_out);
    } else if (ws_size >= WS_BRICKS) {
        uint2* bricks = (uint2*)d_ws;
        int rp_threads = TOTAL_BRICKS * 8;                // 4194304
        repack_fp16_bricks<<<rp_threads / 256, 256, 0, stream>>>((const fx4*)d_in[0], bricks);
        resample_bricks<<<(TOTAL + 255) / 256, 256, 0, stream>>>(bricks, coords, (float4*)d_out);
    } else {
        resample_direct<<<(TOTAL + 255) / 256, 256, 0, stream>>>(
            (const float4*)d_in[0], coords, (float4*)d_out);
    }
}

// Round 8
// 202.881 us; speedup vs baseline: 1.2196x; 1.2196x over previous
//
#include <hip/hip_runtime.h>
#include <hip/hip_fp16.h>

// Problem constants (from reference)
#define BATCH 2
#define NS 128        // input spatial dim (X=Y=Z=128)
#define NB 64         // bricks per dim (2x2x2 voxel bricks, fallback path)
#define ND 96         // output grid per spatial dim

constexpr int PPB   = ND * ND * ND;            // 884736 points per batch
constexpr int TOTAL = BATCH * PPB;             // 1769472
constexpr int BRICKS_PER_BATCH = NB * NB * NB; // 262144
constexpr int TOTAL_BRICKS = BATCH * BRICKS_PER_BATCH;
constexpr size_t WS_BRICKS = (size_t)TOTAL_BRICKS * 64;            // 33.55 MB
constexpr int ENTRIES_PER_BATCH = NS * NS * NS;                    // 2097152
constexpr size_t WS_R4 = (size_t)BATCH * ENTRIES_PER_BATCH * 32;   // 134.2 MB

// native clang vector type: accepted by __builtin_nontemporal_*
typedef float fx4 __attribute__((ext_vector_type(4)));

__device__ __forceinline__ float4 f4_lerp(float4 a, float4 b, float t) {
    float4 r;
    r.x = fmaf(b.x - a.x, t, a.x);
    r.y = fmaf(b.y - a.y, t, a.y);
    r.z = fmaf(b.z - a.z, t, a.z);
    r.w = fmaf(b.w - a.w, t, a.w);
    return r;
}

__device__ __forceinline__ uint2 pack_h4(float x, float y, float z, float w) {
    __half2 h0 = __float22half2_rn(make_float2(x, y));
    __half2 h1 = __float22half2_rn(make_float2(z, w));
    uint2 p;
    p.x = *(const unsigned int*)&h0;
    p.y = *(const unsigned int*)&h1;
    return p;
}

__device__ __forceinline__ float4 unpack_h4(unsigned int a, unsigned int b) {
    float2 f0 = __half22float2(*(const __half2*)&a);
    float2 f1 = __half22float2(*(const __half2*)&b);
    return make_float4(f0.x, f0.y, f1.x, f1.y);
}

// =====================================================================
// R4 table: per-voxel (y,z) 2x2 neighborhood, 32B/entry, x fastest.
// entry(b,y,z,x): lo = [(y,z)|(y,z+1')], hi = [(y+1',z)|(y+1',z+1')]
// with y+1' = min(y+1,127), z+1' = min(z+1,127) (replicate baked in).
// =====================================================================

// ---- Coalesced builder with LDS transpose --------------------------------
// Block = (batch b, y-pair y0..y0+1, z-tile of 16). Loads rows y0..y0+2
// (clamped) x z0..z0+16 (clamped) for ALL 128 x; z-contiguous reads.
// Emits 2*16*128 entries; x-fastest -> contiguous 2KB stores per wave.
#define ZT 16
constexpr int LROWS = 3;            // y0, y0+1, y0+2 (clamped)
constexpr int LZ    = ZT + 1;       // 17 z slots (clamped)
constexpr int LVOX  = 128 * LROWS * LZ;   // 6528 voxels in LDS

__global__ __launch_bounds__(256) void build_r4_table(
    const fx4* __restrict__ in, uint4* __restrict__ tab)
{
    __shared__ uint2 lds[LVOX];     // 52.2 KB, [x][yr][zz], zz fastest

    const int bid = blockIdx.x;
    const int zt = bid & 7;                 // 8 z-tiles
    const int yp = (bid >> 3) & 63;         // 64 y-pairs
    const int b  = bid >> 9;                // 2 batches
    const int z0 = zt * ZT;
    const int y0 = yp * 2;
    const int tid = threadIdx.x;

    // ---- load phase: pack fp32 -> fp16 into LDS --------------------------
    // i = (yr*128 + x)*17 + zz  => lanes 0..16 share (x,yr), contiguous z
    for (int i = tid; i < LVOX; i += 256) {
        int zz   = i % LZ;
        int rest = i / LZ;
        int x    = rest & 127;
        int yr   = rest >> 7;
        int yy   = min(y0 + yr, NS - 1);
        int gz   = min(z0 + zz, NS - 1);
        fx4 v = in[(((size_t)b * NS + x) * NS + yy) * NS + gz];
        lds[x * (LROWS * LZ) + yr * LZ + zz] = pack_h4(v.x, v.y, v.z, v.w);
    }
    __syncthreads();

    // ---- write phase: x fastest -> coalesced 32B entry stores ------------
    // e: x = e&127, z_e = (e>>7)&15, y_e = e>>11
    for (int e = tid; e < 2 * ZT * 128; e += 256) {
        int x   = e & 127;
        int z_e = (e >> 7) & (ZT - 1);
        int y_e = e >> 11;
        int base = x * (LROWS * LZ) + y_e * LZ + z_e;
        uint2 v00 = lds[base];
        uint2 v01 = lds[base + 1];
        uint2 v10 = lds[base + LZ];
        uint2 v11 = lds[base + LZ + 1];

        int gy = y0 + y_e;
        int gz = z0 + z_e;
        size_t eidx = (size_t)b * ENTRIES_PER_BATCH + (((gy << 7) + gz) << 7) + x;
        tab[2 * eidx + 0] = make_uint4(v00.x, v00.y, v01.x, v01.y);
        tab[2 * eidx + 1] = make_uint4(v10.x, v10.y, v11.x, v11.y);
    }
}

// interpolate one point from the R4 table (one batch's sub-table)
__device__ __forceinline__ float4 sample_r4(
    const uint4* __restrict__ tb, float cx, float cy, float cz)
{
    const float fx = floorf(cx), fy = floorf(cy), fz = floorf(cz);
    const float wx = cx - fx;
    // boundary: fy<0 => both y-corners are voxel 0, entry holds rows (0,1) -> w=0
    const float wy = (fy < 0.f) ? 0.f : (cy - fy);
    const float wz = (fz < 0.f) ? 0.f : (cz - fz);

    int x0 = max(0, min((int)fx,     NS - 1));
    int x1 = max(0, min((int)fx + 1, NS - 1));
    int y0 = max(0, min((int)fy,     NS - 1));
    int z0 = max(0, min((int)fz,     NS - 1));

    int ebase = ((y0 << 7) + z0) << 7;    // entry index of (y0,z0,x=0)
    const uint4* e0 = tb + 2 * (ebase + x0);
    const uint4* e1 = tb + 2 * (ebase + x1);

    uint4 lo0 = e0[0], hi0 = e0[1];       // x0: (y0,z0)(y0,z1) | (y1,z0)(y1,z1)
    uint4 lo1 = e1[0], hi1 = e1[1];       // x1

    float4 a00 = unpack_h4(lo0.x, lo0.y), a01 = unpack_h4(lo0.z, lo0.w);
    float4 a10 = unpack_h4(hi0.x, hi0.y), a11 = unpack_h4(hi0.z, hi0.w);
    float4 b00 = unpack_h4(lo1.x, lo1.y), b01 = unpack_h4(lo1.z, lo1.w);
    float4 b10 = unpack_h4(hi1.x, hi1.y), b11 = unpack_h4(hi1.z, hi1.w);

    float4 cA0 = f4_lerp(a00, a01, wz);
    float4 cA1 = f4_lerp(a10, a11, wz);
    float4 cB0 = f4_lerp(b00, b01, wz);
    float4 cB1 = f4_lerp(b10, b11, wz);
    float4 cA  = f4_lerp(cA0, cA1, wy);
    float4 cB  = f4_lerp(cB0, cB1, wy);
    return f4_lerp(cA, cB, wx);
}

__device__ __forceinline__ void nt_store4(float4 v, fx4* p) {
    fx4 t; t.x = v.x; t.y = v.y; t.z = v.z; t.w = v.w;
    __builtin_nontemporal_store(t, p);
}

__global__ __launch_bounds__(256) void resample_r4(
    const uint4* __restrict__ tab,
    const float* __restrict__ coords,
    fx4*         __restrict__ out)
{
    int idx = blockIdx.x * 256 + threadIdx.x;   // 0 .. PPB-1 (grid exact)
    const int idxB = idx + PPB;

    const float axc = coords[3 * idx + 0];
    const float ayc = coords[3 * idx + 1];
    const float azc = coords[3 * idx + 2];
    const float bxc = coords[3 * idxB + 0];
    const float byc = coords[3 * idxB + 1];
    const float bzc = coords[3 * idxB + 2];

    const uint4* tb0 = tab;
    const uint4* tb1 = tab + (size_t)ENTRIES_PER_BATCH * 2;

    float4 rA = sample_r4(tb0, axc, ayc, azc);
    float4 rB = sample_r4(tb1, bxc, byc, bzc);
    nt_store4(rA, &out[idx]);
    nt_store4(rB, &out[idxB]);
}

// =====================================================================
// Fallback 1: fp16 2x2x2 bricks
// =====================================================================
__global__ __launch_bounds__(256) void repack_fp16_bricks(
    const fx4* __restrict__ in, uint2* __restrict__ bricks)
{
    int g = blockIdx.x * 256 + threadIdx.x;
    int t = g >> 3;
    int l = g & 7;
    int lx = (l >> 2) & 1, ly = (l >> 1) & 1, lz = l & 1;
    int b  = t >> 18;
    int r  = t & 262143;
    int x  = ((r >> 12) << 1) + lx;
    int y  = (((r >> 6) & 63) << 1) + ly;
    int z  = ((r & 63) << 1) + lz;

    fx4 v = __builtin_nontemporal_load(&in[(((size_t)b * NS + x) * NS + y) * NS + z]);
    bricks[g] = pack_h4(v.x, v.y, v.z, v.w);
}

__device__ __forceinline__ float4 vox_to_f4(uint2 v) {
    return unpack_h4(v.x, v.y);
}

__device__ __forceinline__ int brick_off(int x, int y, int z) {
    int bidx = (((x >> 1) * NB) + (y >> 1)) * NB + (z >> 1);
    return (bidx << 3) + ((x & 1) << 2) + ((y & 1) << 1) + (z & 1);
}

__global__ __launch_bounds__(256) void resample_bricks(
    const uint2* __restrict__ bricks,
    const float* __restrict__ coords,
    float4*      __restrict__ out)
{
    int idx = blockIdx.x * 256 + threadIdx.x;
    if (idx >= TOTAL) return;

    const float cx = coords[3 * idx + 0];
    const float cy = coords[3 * idx + 1];
    const float cz = coords[3 * idx + 2];
    const float fx = floorf(cx), fy = floorf(cy), fz = floorf(cz);
    const float wx = cx - fx, wy = cy - fy, wz = cz - fz;

    int x0 = max(0, min((int)fx,     NS - 1));
    int x1 = max(0, min((int)fx + 1, NS - 1));
    int y0 = max(0, min((int)fy,     NS - 1));
    int y1 = max(0, min((int)fy + 1, NS - 1));
    int z0 = max(0, min((int)fz,     NS - 1));
    int z1 = max(0, min((int)fz + 1, NS - 1));

    const uint2* __restrict__ wb =
        bricks + ((idx >= PPB) ? (size_t)BRICKS_PER_BATCH * 8 : 0);

    uint2 u000 = wb[brick_off(x0, y0, z0)], u001 = wb[brick_off(x0, y0, z1)];
    uint2 u010 = wb[brick_off(x0, y1, z0)], u011 = wb[brick_off(x0, y1, z1)];
    uint2 u100 = wb[brick_off(x1, y0, z0)], u101 = wb[brick_off(x1, y0, z1)];
    uint2 u110 = wb[brick_off(x1, y1, z0)], u111 = wb[brick_off(x1, y1, z1)];

    float4 c00 = f4_lerp(vox_to_f4(u000), vox_to_f4(u001), wz);
    float4 c01 = f4_lerp(vox_to_f4(u010), vox_to_f4(u011), wz);
    float4 c10 = f4_lerp(vox_to_f4(u100), vox_to_f4(u101), wz);
    float4 c11 = f4_lerp(vox_to_f4(u110), vox_to_f4(u111), wz);
    float4 c0 = f4_lerp(c00, c01, wy);
    float4 c1 = f4_lerp(c10, c11, wy);
    out[idx] = f4_lerp(c0, c1, wx);
}

// =====================================================================
// Fallback 2: direct fp32 gather (no workspace)
// =====================================================================
__global__ __launch_bounds__(256) void resample_direct(
    const float4* __restrict__ in,
    const float*  __restrict__ coords,
    float4*       __restrict__ out)
{
    int idx = blockIdx.x * blockDim.x + threadIdx.x;
    if (idx >= TOTAL) return;

    const float cx = coords[3 * idx + 0];
    const float cy = coords[3 * idx + 1];
    const float cz = coords[3 * idx + 2];
    const float fx = floorf(cx), fy = floorf(cy), fz = floorf(cz);
    const float wx = cx - fx, wy = cy - fy, wz = cz - fz;

    int x0 = max(0, min((int)fx,     NS - 1));
    int x1 = max(0, min((int)fx + 1, NS - 1));
    int y0 = max(0, min((int)fy,     NS - 1));
    int y1 = max(0, min((int)fy + 1, NS - 1));
    int z0 = max(0, min((int)fz,     NS - 1));
    int z1 = max(0, min((int)fz + 1, NS - 1));

    const int b = idx / PPB;
    const float4* __restrict__ inb = in + (size_t)b * (NS * NS * NS);
    const float4* r00 = inb + ((size_t)x0 * NS + y0) * NS;
    const float4* r01 = inb + ((size_t)x0 * NS + y1) * NS;
    const float4* r10 = inb + ((size_t)x1 * NS + y0) * NS;
    const float4* r11 = inb + ((size_t)x1 * NS + y1) * NS;

    float4 c00 = f4_lerp(r00[z0], r00[z1], wz);
    float4 c01 = f4_lerp(r01[z0], r01[z1], wz);
    float4 c10 = f4_lerp(r10[z0], r10[z1], wz);
    float4 c11 = f4_lerp(r11[z0], r11[z1], wz);
    float4 c0 = f4_lerp(c00, c01, wy);
    float4 c1 = f4_lerp(c10, c11, wy);
    out[idx] = f4_lerp(c0, c1, wx);
}

extern "C" void kernel_launch(void* const* d_in, const int* in_sizes, int n_in,
                              void* d_out, int out_size, void* d_ws, size_t ws_size,
                              hipStream_t stream) {
    const float* coords = (const float*)d_in[1];

    if (ws_size >= WS_R4) {
        uint4* tab = (uint4*)d_ws;
        // 2 batches x 64 y-pairs x 8 z-tiles = 1024 blocks
        build_r4_table<<<BATCH * 64 * 8, 256, 0, stream>>>((const fx4*)d_in[0], tab);
        resample_r4<<<PPB / 256, 256, 0, stream>>>(tab, coords, (fx4*)d_out);
    } else if (ws_size >= WS_BRICKS) {
        uint2* bricks = (uint2*)d_ws;
        int rp_threads = TOTAL_BRICKS * 8;                // 4194304
        repack_fp16_bricks<<<rp_threads / 256, 256, 0, stream>>>((const fx4*)d_in[0], bricks);
        resample_bricks<<<(TOTAL + 255) / 256, 256, 0, stream>>>(bricks, coords, (float4*)d_out);
    } else {
        resample_direct<<<(TOTAL + 255) / 256, 256, 0, stream>>>(
            (const float4*)d_in[0], coords, (float4*)d_out);
    }
}

// Round 10
// 186.097 us; speedup vs baseline: 1.3296x; 1.0902x over previous
//
#include <hip/hip_runtime.h>
#include <hip/hip_fp16.h>

// Problem constants (from reference)
#define BATCH 2
#define NS 128        // input spatial dim (X=Y=Z=128)
#define NB 64         // bricks per dim (fallback path)
#define ND 96         // output grid per spatial dim

constexpr int PPB   = ND * ND * ND;            // 884736 points per batch
constexpr int TOTAL = BATCH * PPB;             // 1769472
constexpr int BRICKS_PER_BATCH = NB * NB * NB; // 262144
constexpr int TOTAL_BRICKS = BATCH * BRICKS_PER_BATCH;
constexpr size_t WS_BRICKS = (size_t)TOTAL_BRICKS * 64;            // 33.55 MB
constexpr int ENTRIES_PER_BATCH = NS * NS * NS;                    // 2097152
constexpr size_t WS_R4 = (size_t)BATCH * ENTRIES_PER_BATCH * 32;   // 134.2 MB

// native clang vector type: accepted by __builtin_nontemporal_*
typedef float fx4 __attribute__((ext_vector_type(4)));

__device__ __forceinline__ float4 f4_lerp(float4 a, float4 b, float t) {
    float4 r;
    r.x = fmaf(b.x - a.x, t, a.x);
    r.y = fmaf(b.y - a.y, t, a.y);
    r.z = fmaf(b.z - a.z, t, a.z);
    r.w = fmaf(b.w - a.w, t, a.w);
    return r;
}

__device__ __forceinline__ uint2 pack_h4(float x, float y, float z, float w) {
    __half2 h0 = __float22half2_rn(make_float2(x, y));
    __half2 h1 = __float22half2_rn(make_float2(z, w));
    uint2 p;
    p.x = *(const unsigned int*)&h0;
    p.y = *(const unsigned int*)&h1;
    return p;
}

__device__ __forceinline__ float4 unpack_h4(unsigned int a, unsigned int b) {
    float2 f0 = __half22float2(*(const __half2*)&a);
    float2 f1 = __half22float2(*(const __half2*)&b);
    return make_float4(f0.x, f0.y, f1.x, f1.y);
}

// =====================================================================
// R4 table v2: per-voxel (x,y) 2x2 neighborhood, 32B/entry, Z FASTEST.
// entry(b,x,y,z): lo = [(x,y)|(x+1',y)], hi = [(x,y+1')|(x+1',y+1')]
// with x+1' = min(x+1,127), y+1' = min(y+1,127) (replicate baked in).
// Entry index == builder thread id: g = b*2^21 + x*2^14 + y*2^7 + z.
// Builder: both reads (4 z-contiguous streams) and writes (consecutive
// 32B entries) are natively coalesced -> no LDS, no transpose.
// =====================================================================
__global__ __launch_bounds__(256) void build_r4_table(
    const fx4* __restrict__ in, uint4* __restrict__ tab)
{
    int g = blockIdx.x * 256 + threadIdx.x;   // grid exact: 4194304 threads
    int z = g & 127;
    int y = (g >> 7) & 127;
    int x = (g >> 14) & 127;
    int b = g >> 21;
    int x1 = min(x + 1, NS - 1);
    int y1 = min(y + 1, NS - 1);

    const fx4* __restrict__ inb = in + (size_t)b * (NS * NS * NS);
    fx4 v00 = inb[(((size_t)x  * NS) + y ) * NS + z];   // (x ,y )
    fx4 v10 = inb[(((size_t)x1 * NS) + y ) * NS + z];   // (x1,y )
    fx4 v01 = inb[(((size_t)x  * NS) + y1) * NS + z];   // (x ,y1)
    fx4 v11 = inb[(((size_t)x1 * NS) + y1) * NS + z];   // (x1,y1)

    uint2 p00 = pack_h4(v00.x, v00.y, v00.z, v00.w);
    uint2 p10 = pack_h4(v10.x, v10.y, v10.z, v10.w);
    uint2 p01 = pack_h4(v01.x, v01.y, v01.z, v01.w);
    uint2 p11 = pack_h4(v11.x, v11.y, v11.z, v11.w);

    tab[2 * (size_t)g + 0] = make_uint4(p00.x, p00.y, p10.x, p10.y);
    tab[2 * (size_t)g + 1] = make_uint4(p01.x, p01.y, p11.x, p11.y);
}

// interpolate one point from the R4 table (one batch's sub-table)
__device__ __forceinline__ float4 sample_r4(
    const uint4* __restrict__ tb, float cx, float cy, float cz)
{
    const float fx = floorf(cx), fy = floorf(cy), fz = floorf(cz);
    // boundary: floor<0 => both baked corners are voxel 0 -> force weight 0.
    // (z needs no fix: z0,z1 are clamped independently; when equal, the
    //  two entries coincide and the z-lerp is degenerate.)
    const float wx = (fx < 0.f) ? 0.f : (cx - fx);
    const float wy = (fy < 0.f) ? 0.f : (cy - fy);
    const float wz = cz - fz;

    int x0 = max(0, min((int)fx, NS - 1));
    int y0 = max(0, min((int)fy, NS - 1));
    int z0 = max(0, min((int)fz,     NS - 1));
    int z1 = max(0, min((int)fz + 1, NS - 1));

    int ebase = ((x0 << 7) + y0) << 7;    // entry index of (x0,y0,z=0)
    const uint4* e0 = tb + 2 * (size_t)(ebase + z0);
    const uint4* e1 = tb + 2 * (size_t)(ebase + z1);

    uint4 lo0 = e0[0], hi0 = e0[1];   // z0: (x0,y0)(x1,y0) | (x0,y1)(x1,y1)
    uint4 lo1 = e1[0], hi1 = e1[1];   // z1

    float4 c000 = unpack_h4(lo0.x, lo0.y), c100 = unpack_h4(lo0.z, lo0.w);
    float4 c010 = unpack_h4(hi0.x, hi0.y), c110 = unpack_h4(hi0.z, hi0.w);
    float4 c001 = unpack_h4(lo1.x, lo1.y), c101 = unpack_h4(lo1.z, lo1.w);
    float4 c011 = unpack_h4(hi1.x, hi1.y), c111 = unpack_h4(hi1.z, hi1.w);

    float4 d00 = f4_lerp(c000, c001, wz);   // (x0,y0)
    float4 d10 = f4_lerp(c100, c101, wz);   // (x1,y0)
    float4 d01 = f4_lerp(c010, c011, wz);   // (x0,y1)
    float4 d11 = f4_lerp(c110, c111, wz);   // (x1,y1)

    float4 e0y = f4_lerp(d00, d01, wy);     // x0
    float4 e1y = f4_lerp(d10, d11, wy);     // x1
    return f4_lerp(e0y, e1y, wx);
}

__device__ __forceinline__ void nt_store4(float4 v, fx4* p) {
    fx4 t; t.x = v.x; t.y = v.y; t.z = v.z; t.w = v.w;
    __builtin_nontemporal_store(t, p);
}

__global__ __launch_bounds__(256) void resample_r4(
    const uint4* __restrict__ tab,
    const float* __restrict__ coords,
    fx4*         __restrict__ out)
{
    int idx = blockIdx.x * 256 + threadIdx.x;   // 0 .. PPB-1 (grid exact)
    const int idxB = idx + PPB;

    const float axc = coords[3 * idx + 0];
    const float ayc = coords[3 * idx + 1];
    const float azc = coords[3 * idx + 2];
    const float bxc = coords[3 * idxB + 0];
    const float byc = coords[3 * idxB + 1];
    const float bzc = coords[3 * idxB + 2];

    const uint4* tb0 = tab;
    const uint4* tb1 = tab + (size_t)ENTRIES_PER_BATCH * 2;

    float4 rA = sample_r4(tb0, axc, ayc, azc);
    float4 rB = sample_r4(tb1, bxc, byc, bzc);
    nt_store4(rA, &out[idx]);
    nt_store4(rB, &out[idxB]);
}

// =====================================================================
// Fallback 1: fp16 2x2x2 bricks
// =====================================================================
__global__ __launch_bounds__(256) void repack_fp16_bricks(
    const fx4* __restrict__ in, uint2* __restrict__ bricks)
{
    int g = blockIdx.x * 256 + threadIdx.x;
    int t = g >> 3;
    int l = g & 7;
    int lx = (l >> 2) & 1, ly = (l >> 1) & 1, lz = l & 1;
    int b  = t >> 18;
    int r  = t & 262143;
    int x  = ((r >> 12) << 1) + lx;
    int y  = (((r >> 6) & 63) << 1) + ly;
    int z  = ((r & 63) << 1) + lz;

    fx4 v = __builtin_nontemporal_load(&in[(((size_t)b * NS + x) * NS + y) * NS + z]);
    bricks[g] = pack_h4(v.x, v.y, v.z, v.w);
}

__device__ __forceinline__ float4 vox_to_f4(uint2 v) {
    return unpack_h4(v.x, v.y);
}

__device__ __forceinline__ int brick_off(int x, int y, int z) {
    int bidx = (((x >> 1) * NB) + (y >> 1)) * NB + (z >> 1);
    return (bidx << 3) + ((x & 1) << 2) + ((y & 1) << 1) + (z & 1);
}

__global__ __launch_bounds__(256) void resample_bricks(
    const uint2* __restrict__ bricks,
    const float* __restrict__ coords,
    float4*      __restrict__ out)
{
    int idx = blockIdx.x * 256 + threadIdx.x;
    if (idx >= TOTAL) return;

    const float cx = coords[3 * idx + 0];
    const float cy = coords[3 * idx + 1];
    const float cz = coords[3 * idx + 2];
    const float fx = floorf(cx), fy = floorf(cy), fz = floorf(cz);
    const float wx = cx - fx, wy = cy - fy, wz = cz - fz;

    int x0 = max(0, min((int)fx,     NS - 1));
    int x1 = max(0, min((int)fx + 1, NS - 1));
    int y0 = max(0, min((int)fy,     NS - 1));
    int y1 = max(0, min((int)fy + 1, NS - 1));
    int z0 = max(0, min((int)fz,     NS - 1));
    int z1 = max(0, min((int)fz + 1, NS - 1));

    const uint2* __restrict__ wb =
        bricks + ((idx >= PPB) ? (size_t)BRICKS_PER_BATCH * 8 : 0);

    uint2 u000 = wb[brick_off(x0, y0, z0)], u001 = wb[brick_off(x0, y0, z1)];
    uint2 u010 = wb[brick_off(x0, y1, z0)], u011 = wb[brick_off(x0, y1, z1)];
    uint2 u100 = wb[brick_off(x1, y0, z0)], u101 = wb[brick_off(x1, y0, z1)];
    uint2 u110 = wb[brick_off(x1, y1, z0)], u111 = wb[brick_off(x1, y1, z1)];

    float4 c00 = f4_lerp(vox_to_f4(u000), vox_to_f4(u001), wz);
    float4 c01 = f4_lerp(vox_to_f4(u010), vox_to_f4(u011), wz);
    float4 c10 = f4_lerp(vox_to_f4(u100), vox_to_f4(u101), wz);
    float4 c11 = f4_lerp(vox_to_f4(u110), vox_to_f4(u111), wz);
    float4 c0 = f4_lerp(c00, c01, wy);
    float4 c1 = f4_lerp(c10, c11, wy);
    out[idx] = f4_lerp(c0, c1, wx);
}

// =====================================================================
// Fallback 2: direct fp32 gather (no workspace)
// =====================================================================
__global__ __launch_bounds__(256) void resample_direct(
    const float4* __restrict__ in,
    const float*  __restrict__ coords,
    float4*       __restrict__ out)
{
    int idx = blockIdx.x * blockDim.x + threadIdx.x;
    if (idx >= TOTAL) return;

    const float cx = coords[3 * idx + 0];
    const float cy = coords[3 * idx + 1];
    const float cz = coords[3 * idx + 2];
    const float fx = floorf(cx), fy = floorf(cy), fz = floorf(cz);
    const float wx = cx - fx, wy = cy - fy, wz = cz - fz;

    int x0 = max(0, min((int)fx,     NS - 1));
    int x1 = max(0, min((int)fx + 1, NS - 1));
    int y0 = max(0, min((int)fy,     NS - 1));
    int y1 = max(0, min((int)fy + 1, NS - 1));
    int z0 = max(0, min((int)fz,     NS - 1));
    int z1 = max(0, min((int)fz + 1, NS - 1));

    const int b = idx / PPB;
    const float4* __restrict__ inb = in + (size_t)b * (NS * NS * NS);
    const float4* r00 = inb + ((size_t)x0 * NS + y0) * NS;
    const float4* r01 = inb + ((size_t)x0 * NS + y1) * NS;
    const float4* r10 = inb + ((size_t)x1 * NS + y0) * NS;
    const float4* r11 = inb + ((size_t)x1 * NS + y1) * NS;

    float4 c00 = f4_lerp(r00[z0], r00[z1], wz);
    float4 c01 = f4_lerp(r01[z0], r01[z1], wz);
    float4 c10 = f4_lerp(r10[z0], r10[z1], wz);
    float4 c11 = f4_lerp(r11[z0], r11[z1], wz);
    float4 c0 = f4_lerp(c00, c01, wy);
    float4 c1 = f4_lerp(c10, c11, wy);
    out[idx] = f4_lerp(c0, c1, wx);
}

extern "C" void kernel_launch(void* const* d_in, const int* in_sizes, int n_in,
                              void* d_out, int out_size, void* d_ws, size_t ws_size,
                              hipStream_t stream) {
    const float* coords = (const float*)d_in[1];

    if (ws_size >= WS_R4) {
        uint4* tab = (uint4*)d_ws;
        int entries = BATCH * ENTRIES_PER_BATCH;          // 4194304
        build_r4_table<<<entries / 256, 256, 0, stream>>>((const fx4*)d_in[0], tab);
        resample_r4<<<PPB / 256, 256, 0, stream>>>(tab, coords, (fx4*)d_out);
    } else if (ws_size >= WS_BRICKS) {
        uint2* bricks = (uint2*)d_ws;
        int rp_threads = TOTAL_BRICKS * 8;                // 4194304
        repack_fp16_bricks<<<rp_threads / 256, 256, 0, stream>>>((const fx4*)d_in[0], bricks);
        resample_bricks<<<(TOTAL + 255) / 256, 256, 0, stream>>>(bricks, coords, (float4*)d_out);
    } else {
        resample_direct<<<(TOTAL + 255) / 256, 256, 0, stream>>>(
            (const float4*)d_in[0], coords, (float4*)d_out);
    }
}